// Round 1
// baseline (785.591 us; speedup 1.0000x reference)
//
#include <hip/hip_runtime.h>
#include <hip/hip_bf16.h>

#define BROWS 32768
#define HDIM 512
#define DIN 1024
#define HB ((size_t)BROWS * HDIM)

typedef __attribute__((ext_vector_type(8))) __bf16 bf16x8;
typedef __attribute__((ext_vector_type(4))) float f32x4;
typedef __attribute__((ext_vector_type(8))) unsigned short us8;

__device__ inline unsigned short f2bf(float f) {
    union { float f; unsigned u; } v; v.f = f;
    unsigned r = v.u + 0x7fff + ((v.u >> 16) & 1);
    return (unsigned short)(r >> 16);
}
__device__ inline float bf2f(unsigned short b) {
    union { unsigned u; float f; } v; v.u = ((unsigned)b) << 16;
    return v.f;
}
__device__ inline float sigm(float z) { return 1.0f / (1.0f + __expf(-z)); }
__device__ inline float tanhfast(float z) { return 1.0f - 2.0f / (__expf(2.0f * z) + 1.0f); }

__device__ inline void gload_lds16(const void* gp, void* lp) {
    __builtin_amdgcn_global_load_lds((const __attribute__((address_space(1))) void*)gp,
                                     (__attribute__((address_space(3))) void*)lp, 16, 0, 0);
}

// ---------------- prep: xh = bf16([x | h]) ----------------
__global__ void cvt_xh(const float* __restrict__ x, const float* __restrict__ h,
                       unsigned short* __restrict__ xh) {
    const size_t total8 = (size_t)BROWS * DIN / 8;
    size_t stride = (size_t)gridDim.x * blockDim.x;
    for (size_t i = (size_t)blockIdx.x * blockDim.x + threadIdx.x; i < total8; i += stride) {
        size_t e = i * 8;
        size_t r = e >> 10;
        int k = (int)(e & 1023);
        const float* s = (k < HDIM) ? (x + r * HDIM + k) : (h + r * HDIM + (k - HDIM));
        f32x4 a = *(const f32x4*)s;
        f32x4 b = *(const f32x4*)(s + 4);
        us8 o;
        o[0] = f2bf(a[0]); o[1] = f2bf(a[1]); o[2] = f2bf(a[2]); o[3] = f2bf(a[3]);
        o[4] = f2bf(b[0]); o[5] = f2bf(b[1]); o[6] = f2bf(b[2]); o[7] = f2bf(b[3]);
        *(us8*)(xh + e) = o;
    }
}

// ---------------- prep: Wt[n][k] = bf16(W[k][n]), 6 matrices ----------------
struct WP { const float* w[6]; };

__global__ void wtrans(WP p, unsigned short* __restrict__ wt) {
    __shared__ float tile[64][65];
    const float* src = p.w[blockIdx.z];
    unsigned short* dst = wt + ((size_t)blockIdx.z << 19);
    int n0 = blockIdx.x * 64, k0 = blockIdx.y * 64;
    int t = threadIdx.x, r = t >> 2, q = t & 3;
    const float* s = src + (size_t)(k0 + r) * HDIM + n0 + q * 16;
#pragma unroll
    for (int j = 0; j < 16; j += 4) {
        f32x4 v = *(const f32x4*)(s + j);
        tile[r][q * 16 + j + 0] = v[0];
        tile[r][q * 16 + j + 1] = v[1];
        tile[r][q * 16 + j + 2] = v[2];
        tile[r][q * 16 + j + 3] = v[3];
    }
    __syncthreads();
    us8 o0, o1;
#pragma unroll
    for (int j = 0; j < 8; ++j) o0[j] = f2bf(tile[q * 16 + j][r]);
#pragma unroll
    for (int j = 0; j < 8; ++j) o1[j] = f2bf(tile[q * 16 + 8 + j][r]);
    unsigned short* d = dst + (size_t)(n0 + r) * DIN + k0 + q * 16;
    *(us8*)d = o0;
    *(us8*)(d + 8) = o1;
}

// ---------------- GEMM1: gates + fused LSTM elementwise ----------------
// block: 128 rows x (32 cols x 5 gates), BK=64, 256 thr (4 waves, 2x2)
__global__ __launch_bounds__(256) void gemm_gates(
    const unsigned short* __restrict__ xh, const unsigned short* __restrict__ wt,
    const float* __restrict__ bi, const float* __restrict__ bf_,
    const float* __restrict__ bo, const float* __restrict__ bg1,
    const float* __restrict__ bg2,
    const float* __restrict__ cin, const float* __restrict__ Cin,
    float* __restrict__ out, unsigned short* __restrict__ obuf) {
    __shared__ __align__(16) unsigned short As[128][64];
    __shared__ __align__(16) unsigned short Bs[5][32][64];

    int bid = blockIdx.x;                       // 4096, %8==0 -> bijective XCD chunk
    int wg = (bid & 7) * 512 + (bid >> 3);
    int mb = wg >> 4, nb = wg & 15;
    int r0 = mb * 128;
    int n0 = nb * 32;
    int t = threadIdx.x;
    int wv = t >> 6, lane = t & 63;
    int wr = wv >> 1, wc = wv & 1;              // wave: 64 rows x 16 cols (per gate)

    f32x4 acc[5][4] = {};

    for (int kt = 0; kt < DIN / 64; ++kt) {
        int k0 = kt * 64;
        // A: 16 chunks of 8 rows (1KB each), swizzled source
#pragma unroll
        for (int i = 0; i < 4; ++i) {
            int ci = wv * 4 + i;
            int row = ci * 8 + (lane >> 3);
            int kc = (lane & 7) ^ (row & 7);
            const unsigned short* gp = xh + (size_t)(r0 + row) * DIN + k0 + kc * 8;
            gload_lds16(gp, &As[ci * 8][0]);
        }
        // B: 5 gates x 4 chunks
#pragma unroll
        for (int i = 0; i < 5; ++i) {
            int q = wv * 5 + i;
            int g = q >> 2, rb = q & 3;
            int row = rb * 8 + (lane >> 3);
            int kc = (lane & 7) ^ (row & 7);
            const unsigned short* gp = wt + ((size_t)g << 19) + (size_t)(n0 + row) * DIN + k0 + kc * 8;
            gload_lds16(gp, &Bs[g][rb * 8][0]);
        }
        __syncthreads();
#pragma unroll
        for (int kk = 0; kk < 2; ++kk) {
            bf16x8 a[4];
#pragma unroll
            for (int m = 0; m < 4; ++m) {
                int row = wr * 64 + m * 16 + (lane & 15);
                int chunk = kk * 4 + (lane >> 4);
                int off = row * 128 + ((chunk ^ (row & 7)) << 4);
                a[m] = *(const bf16x8*)((const char*)&As[0][0] + off);
            }
#pragma unroll
            for (int g = 0; g < 5; ++g) {
                int row = wc * 16 + (lane & 15);
                int chunk = kk * 4 + (lane >> 4);
                int off = row * 128 + ((chunk ^ (row & 7)) << 4);
                bf16x8 b = *(const bf16x8*)((const char*)&Bs[g][0][0] + off);
#pragma unroll
                for (int m = 0; m < 4; ++m)
                    acc[g][m] = __builtin_amdgcn_mfma_f32_16x16x32_bf16(a[m], b, acc[g][m], 0, 0, 0);
            }
        }
        __syncthreads();
    }

    // epilogue: C/D layout col=lane&15, row=(lane>>4)*4+j
    int cg = n0 + wc * 16 + (lane & 15);
    float vbi = bi[cg], vbf = bf_[cg], vbo = bo[cg], vbg1 = bg1[cg], vbg2 = bg2[cg];
#pragma unroll
    for (int m = 0; m < 4; ++m) {
        int rbase = r0 + wr * 64 + m * 16 + ((lane >> 4) << 2);
#pragma unroll
        for (int j = 0; j < 4; ++j) {
            size_t off = (size_t)(rbase + j) * HDIM + cg;
            float iv = sigm(acc[0][m][j] + vbi);
            float fv = sigm(acc[1][m][j] + vbf);
            float ov = sigm(acc[2][m][j] + vbo);
            float g1 = tanhfast(acc[3][m][j] + vbg1);
            float g2 = tanhfast(acc[4][m][j] + vbg2);
            float cell = cin[off], Cc = Cin[off];
            out[HB + off] = fv * cell + iv * g1;
            out[2 * HB + off] = fv * Cc + iv * g2;
            obuf[off] = f2bf(ov);
        }
    }
}

// ---------------- GEMM2: cc @ W_mlp, fused o*tanh epilogue ----------------
// block: 128 rows x 64 cols, BK=64, 256 thr (4 waves, 2x2)
__global__ __launch_bounds__(256) void gemm_mlp(
    const float* __restrict__ outbase, const unsigned short* __restrict__ wtm,
    const float* __restrict__ bm, const unsigned short* __restrict__ obuf,
    float* __restrict__ out) {
    __shared__ __align__(16) unsigned short As[128][64];
    __shared__ __align__(16) unsigned short Bs[64][64];

    int bid = blockIdx.x;                       // 2048
    int wg = (bid & 7) * 256 + (bid >> 3);
    int mb = wg >> 3, nb = wg & 7;
    int r0 = mb * 128, n0 = nb * 64;
    int t = threadIdx.x, wv = t >> 6, lane = t & 63;
    int wr = wv >> 1, wc = wv & 1;              // wave: 64 rows x 32 cols

    f32x4 acc[4][2] = {};

    for (int kt = 0; kt < 16; ++kt) {
        int k0 = kt * 64;
        const float* asrc = (kt < 8) ? (outbase + HB) : (outbase + 2 * HB);
        int kcol = k0 & (HDIM - 1);
        // reg-stage A (f32 -> bf16, swizzled ds_write)
        {
            int row = t >> 1, half = t & 1;
            const float* s = asrc + (size_t)(r0 + row) * HDIM + kcol + half * 32;
            unsigned short tmp[32];
#pragma unroll
            for (int j = 0; j < 32; j += 4) {
                f32x4 v = *(const f32x4*)(s + j);
                tmp[j] = f2bf(v[0]); tmp[j + 1] = f2bf(v[1]);
                tmp[j + 2] = f2bf(v[2]); tmp[j + 3] = f2bf(v[3]);
            }
#pragma unroll
            for (int cj = 0; cj < 4; ++cj) {
                int chunk = half * 4 + cj;
                int off = row * 128 + ((chunk ^ (row & 7)) << 4);
                *(us8*)((char*)&As[0][0] + off) = *(const us8*)&tmp[cj * 8];
            }
        }
        // B: 8 chunks, 2 per wave
#pragma unroll
        for (int i = 0; i < 2; ++i) {
            int rb = wv * 2 + i;
            int row = rb * 8 + (lane >> 3);
            int kc = (lane & 7) ^ (row & 7);
            const unsigned short* gp = wtm + (size_t)(n0 + row) * DIN + k0 + kc * 8;
            gload_lds16(gp, &Bs[rb * 8][0]);
        }
        __syncthreads();
#pragma unroll
        for (int kk = 0; kk < 2; ++kk) {
            bf16x8 a[4];
#pragma unroll
            for (int m = 0; m < 4; ++m) {
                int row = wr * 64 + m * 16 + (lane & 15);
                int chunk = kk * 4 + (lane >> 4);
                int off = row * 128 + ((chunk ^ (row & 7)) << 4);
                a[m] = *(const bf16x8*)((const char*)&As[0][0] + off);
            }
#pragma unroll
            for (int n = 0; n < 2; ++n) {
                int row = wc * 32 + n * 16 + (lane & 15);
                int chunk = kk * 4 + (lane >> 4);
                int off = row * 128 + ((chunk ^ (row & 7)) << 4);
                bf16x8 b = *(const bf16x8*)((const char*)&Bs[0][0] + off);
#pragma unroll
                for (int m = 0; m < 4; ++m)
                    acc[m][n] = __builtin_amdgcn_mfma_f32_16x16x32_bf16(a[m], b, acc[m][n], 0, 0, 0);
            }
        }
        __syncthreads();
    }

#pragma unroll
    for (int n = 0; n < 2; ++n) {
        int cg = n0 + wc * 32 + n * 16 + (lane & 15);
        float vb = bm[cg];
#pragma unroll
        for (int m = 0; m < 4; ++m) {
            int rbase = r0 + wr * 64 + m * 16 + ((lane >> 4) << 2);
#pragma unroll
            for (int j = 0; j < 4; ++j) {
                size_t off = (size_t)(rbase + j) * HDIM + cg;
                float z = acc[m][n][j] + vb;
                out[off] = bf2f(obuf[off]) * tanhfast(z);
            }
        }
    }
}

extern "C" void kernel_launch(void* const* d_in, const int* in_sizes, int n_in,
                              void* d_out, int out_size, void* d_ws, size_t ws_size,
                              hipStream_t stream) {
    const float* x  = (const float*)d_in[0];
    const float* h  = (const float*)d_in[1];
    const float* c  = (const float*)d_in[2];
    const float* C  = (const float*)d_in[3];
    const float* Wi = (const float*)d_in[4];  const float* bi  = (const float*)d_in[5];
    const float* Wf = (const float*)d_in[6];  const float* bf  = (const float*)d_in[7];
    const float* Wo = (const float*)d_in[8];  const float* bo  = (const float*)d_in[9];
    const float* Wg1 = (const float*)d_in[10]; const float* bg1 = (const float*)d_in[11];
    const float* Wg2 = (const float*)d_in[12]; const float* bg2 = (const float*)d_in[13];
    const float* Wm = (const float*)d_in[14]; const float* bm  = (const float*)d_in[15];
    float* out = (float*)d_out;

    unsigned short* wt   = (unsigned short*)d_ws;            // 6 x [512][1024] bf16 = 6 MB
    unsigned short* xh   = wt + (6u << 19);                  // [32768][1024] bf16 = 64 MB
    unsigned short* obuf = xh + (size_t)BROWS * DIN;         // [32768][512]  bf16 = 32 MB

    WP wp;
    wp.w[0] = Wi; wp.w[1] = Wf; wp.w[2] = Wo; wp.w[3] = Wg1; wp.w[4] = Wg2; wp.w[5] = Wm;

    cvt_xh<<<dim3(4096), dim3(256), 0, stream>>>(x, h, xh);
    wtrans<<<dim3(8, 16, 6), dim3(256), 0, stream>>>(wp, wt);
    gemm_gates<<<dim3(4096), dim3(256), 0, stream>>>(xh, wt, bi, bf, bo, bg1, bg2, c, C, out, obuf);
    gemm_mlp<<<dim3(2048), dim3(256), 0, stream>>>(out, wt + (5u << 19), bm, obuf, out);
}

// Round 2
// 779.434 us; speedup vs baseline: 1.0079x; 1.0079x over previous
//
#include <hip/hip_runtime.h>
#include <hip/hip_bf16.h>

#define BROWS 32768
#define HDIM 512
#define DIN 1024
#define HB ((size_t)BROWS * HDIM)

typedef __attribute__((ext_vector_type(8))) __bf16 bf16x8;
typedef __attribute__((ext_vector_type(4))) float f32x4;
typedef __attribute__((ext_vector_type(8))) unsigned short us8;

__device__ inline unsigned short f2bf(float f) {
    union { float f; unsigned u; } v; v.f = f;
    unsigned r = v.u + 0x7fff + ((v.u >> 16) & 1);
    return (unsigned short)(r >> 16);
}
__device__ inline float bf2f(unsigned short b) {
    union { unsigned u; float f; } v; v.u = ((unsigned)b) << 16;
    return v.f;
}
__device__ inline float sigm(float z) { return 1.0f / (1.0f + __expf(-z)); }
__device__ inline float tanhfast(float z) { return 1.0f - 2.0f / (__expf(2.0f * z) + 1.0f); }

__device__ inline void gload_lds16(const void* gp, void* lp) {
    __builtin_amdgcn_global_load_lds((const __attribute__((address_space(1))) void*)gp,
                                     (__attribute__((address_space(3))) void*)lp, 16, 0, 0);
}

// ---------------- prep: xh = bf16([x | h]) ----------------
__global__ void cvt_xh(const float* __restrict__ x, const float* __restrict__ h,
                       unsigned short* __restrict__ xh) {
    const size_t total8 = (size_t)BROWS * DIN / 8;
    size_t stride = (size_t)gridDim.x * blockDim.x;
    for (size_t i = (size_t)blockIdx.x * blockDim.x + threadIdx.x; i < total8; i += stride) {
        size_t e = i * 8;
        size_t r = e >> 10;
        int k = (int)(e & 1023);
        const float* s = (k < HDIM) ? (x + r * HDIM + k) : (h + r * HDIM + (k - HDIM));
        f32x4 a = *(const f32x4*)s;
        f32x4 b = *(const f32x4*)(s + 4);
        us8 o;
        o[0] = f2bf(a[0]); o[1] = f2bf(a[1]); o[2] = f2bf(a[2]); o[3] = f2bf(a[3]);
        o[4] = f2bf(b[0]); o[5] = f2bf(b[1]); o[6] = f2bf(b[2]); o[7] = f2bf(b[3]);
        *(us8*)(xh + e) = o;
    }
}

// ---------------- prep: Wt[n][k] = bf16(W[k][n]), 6 matrices ----------------
struct WP { const float* w[6]; };

__global__ void wtrans(WP p, unsigned short* __restrict__ wt) {
    __shared__ float tile[64][65];
    const float* src = p.w[blockIdx.z];
    unsigned short* dst = wt + ((size_t)blockIdx.z << 19);
    int n0 = blockIdx.x * 64, k0 = blockIdx.y * 64;
    int t = threadIdx.x, r = t >> 2, q = t & 3;
    const float* s = src + (size_t)(k0 + r) * HDIM + n0 + q * 16;
#pragma unroll
    for (int j = 0; j < 16; j += 4) {
        f32x4 v = *(const f32x4*)(s + j);
        tile[r][q * 16 + j + 0] = v[0];
        tile[r][q * 16 + j + 1] = v[1];
        tile[r][q * 16 + j + 2] = v[2];
        tile[r][q * 16 + j + 3] = v[3];
    }
    __syncthreads();
    us8 o0, o1;
#pragma unroll
    for (int j = 0; j < 8; ++j) o0[j] = f2bf(tile[q * 16 + j][r]);
#pragma unroll
    for (int j = 0; j < 8; ++j) o1[j] = f2bf(tile[q * 16 + 8 + j][r]);
    unsigned short* d = dst + (size_t)(n0 + r) * DIN + k0 + q * 16;
    *(us8*)d = o0;
    *(us8*)(d + 8) = o1;
}

// ---------------- GEMM1: gates + fused LSTM elementwise ----------------
// block: 128 rows x (32 cols x 5 gates), BK=64, 256 thr (4 waves, 2x2)
// 2-phase double-buffered (T3-minimum): STAGE(next) -> compute(cur) -> 1 barrier
__global__ __launch_bounds__(256) void gemm_gates(
    const unsigned short* __restrict__ xh, const unsigned short* __restrict__ wt,
    const float* __restrict__ bi, const float* __restrict__ bf_,
    const float* __restrict__ bo, const float* __restrict__ bg1,
    const float* __restrict__ bg2,
    const float* __restrict__ cin, const float* __restrict__ Cin,
    float* __restrict__ out, unsigned short* __restrict__ obuf,
    unsigned short* __restrict__ ccbuf) {
    __shared__ __align__(16) unsigned short As[2][128][64];
    __shared__ __align__(16) unsigned short Bs[2][5][32][64];

    int bid = blockIdx.x;                       // 4096, %8==0 -> bijective XCD chunk
    int wg = (bid & 7) * 512 + (bid >> 3);
    int mb = wg >> 4, nb = wg & 15;
    int r0 = mb * 128;
    int n0 = nb * 32;
    int t = threadIdx.x;
    int wv = t >> 6, lane = t & 63;
    int wr = wv >> 1, wc = wv & 1;              // wave: 64 rows x 16 cols (per gate)

    f32x4 acc[5][4] = {};

    auto stage = [&](int kt, int b) {
        int k0 = kt * 64;
#pragma unroll
        for (int i = 0; i < 4; ++i) {
            int ci = wv * 4 + i;
            int row = ci * 8 + (lane >> 3);
            int kc = (lane & 7) ^ (row & 7);
            const unsigned short* gp = xh + (size_t)(r0 + row) * DIN + k0 + kc * 8;
            gload_lds16(gp, &As[b][ci * 8][0]);
        }
#pragma unroll
        for (int i = 0; i < 5; ++i) {
            int q = wv * 5 + i;
            int g = q >> 2, rb = q & 3;
            int row = rb * 8 + (lane >> 3);
            int kc = (lane & 7) ^ (row & 7);
            const unsigned short* gp = wt + ((size_t)g << 19) + (size_t)(n0 + row) * DIN + k0 + kc * 8;
            gload_lds16(gp, &Bs[b][g][rb * 8][0]);
        }
    };

    stage(0, 0);
    __syncthreads();

    int cur = 0;
    for (int kt = 0; kt < DIN / 64; ++kt) {
        if (kt < DIN / 64 - 1) stage(kt + 1, cur ^ 1);
#pragma unroll
        for (int kk = 0; kk < 2; ++kk) {
            bf16x8 a[4];
#pragma unroll
            for (int m = 0; m < 4; ++m) {
                int row = wr * 64 + m * 16 + (lane & 15);
                int chunk = kk * 4 + (lane >> 4);
                int off = row * 128 + ((chunk ^ (row & 7)) << 4);
                a[m] = *(const bf16x8*)((const char*)&As[cur][0][0] + off);
            }
#pragma unroll
            for (int g = 0; g < 5; ++g) {
                int row = wc * 16 + (lane & 15);
                int chunk = kk * 4 + (lane >> 4);
                int off = row * 128 + ((chunk ^ (row & 7)) << 4);
                bf16x8 b = *(const bf16x8*)((const char*)&Bs[cur][g][0][0] + off);
#pragma unroll
                for (int m = 0; m < 4; ++m)
                    acc[g][m] = __builtin_amdgcn_mfma_f32_16x16x32_bf16(a[m], b, acc[g][m], 0, 0, 0);
            }
        }
        __syncthreads();   // drains vmcnt (stage) + lgkmcnt; next buffer ready
        cur ^= 1;
    }

    // epilogue: C/D layout col=lane&15, row=(lane>>4)*4+j
    int cg = n0 + wc * 16 + (lane & 15);
    float vbi = bi[cg], vbf = bf_[cg], vbo = bo[cg], vbg1 = bg1[cg], vbg2 = bg2[cg];
#pragma unroll
    for (int m = 0; m < 4; ++m) {
        int rbase = r0 + wr * 64 + m * 16 + ((lane >> 4) << 2);
#pragma unroll
        for (int j = 0; j < 4; ++j) {
            size_t off = (size_t)(rbase + j) * HDIM + cg;
            float iv = sigm(acc[0][m][j] + vbi);
            float fv = sigm(acc[1][m][j] + vbf);
            float ov = sigm(acc[2][m][j] + vbo);
            float g1 = tanhfast(acc[3][m][j] + vbg1);
            float g2 = tanhfast(acc[4][m][j] + vbg2);
            float ncv = fv * cin[off] + iv * g1;
            float nCv = fv * Cin[off] + iv * g2;
            out[HB + off] = ncv;
            out[2 * HB + off] = nCv;
            obuf[off] = f2bf(ov);
            size_t ccoff = (size_t)(rbase + j) * DIN + cg;
            ccbuf[ccoff] = f2bf(ncv);
            ccbuf[ccoff + HDIM] = f2bf(nCv);
        }
    }
}

// ---------------- GEMM2: cc @ W_mlp, fused o*tanh epilogue ----------------
// block: 128 rows x 64 cols, BK=64, 256 thr (4 waves, 2x2), 2-phase dbuf
__global__ __launch_bounds__(256) void gemm_mlp(
    const unsigned short* __restrict__ ccbuf, const unsigned short* __restrict__ wtm,
    const float* __restrict__ bm, const unsigned short* __restrict__ obuf,
    float* __restrict__ out) {
    __shared__ __align__(16) unsigned short As[2][128][64];
    __shared__ __align__(16) unsigned short Bs[2][64][64];

    int bid = blockIdx.x;                       // 2048
    int wg = (bid & 7) * 256 + (bid >> 3);
    int mb = wg >> 3, nb = wg & 7;
    int r0 = mb * 128, n0 = nb * 64;
    int t = threadIdx.x, wv = t >> 6, lane = t & 63;
    int wr = wv >> 1, wc = wv & 1;              // wave: 64 rows x 32 cols

    f32x4 acc[4][2] = {};

    auto stage = [&](int kt, int b) {
        int k0 = kt * 64;
#pragma unroll
        for (int i = 0; i < 4; ++i) {
            int ci = wv * 4 + i;
            int row = ci * 8 + (lane >> 3);
            int kc = (lane & 7) ^ (row & 7);
            const unsigned short* gp = ccbuf + (size_t)(r0 + row) * DIN + k0 + kc * 8;
            gload_lds16(gp, &As[b][ci * 8][0]);
        }
#pragma unroll
        for (int i = 0; i < 2; ++i) {
            int rb = wv * 2 + i;
            int row = rb * 8 + (lane >> 3);
            int kc = (lane & 7) ^ (row & 7);
            const unsigned short* gp = wtm + (size_t)(n0 + row) * DIN + k0 + kc * 8;
            gload_lds16(gp, &Bs[b][rb * 8][0]);
        }
    };

    stage(0, 0);
    __syncthreads();

    int cur = 0;
    for (int kt = 0; kt < 16; ++kt) {
        if (kt < 15) stage(kt + 1, cur ^ 1);
#pragma unroll
        for (int kk = 0; kk < 2; ++kk) {
            bf16x8 a[4];
#pragma unroll
            for (int m = 0; m < 4; ++m) {
                int row = wr * 64 + m * 16 + (lane & 15);
                int chunk = kk * 4 + (lane >> 4);
                int off = row * 128 + ((chunk ^ (row & 7)) << 4);
                a[m] = *(const bf16x8*)((const char*)&As[cur][0][0] + off);
            }
#pragma unroll
            for (int n = 0; n < 2; ++n) {
                int row = wc * 32 + n * 16 + (lane & 15);
                int chunk = kk * 4 + (lane >> 4);
                int off = row * 128 + ((chunk ^ (row & 7)) << 4);
                bf16x8 b = *(const bf16x8*)((const char*)&Bs[cur][0][0] + off);
#pragma unroll
                for (int m = 0; m < 4; ++m)
                    acc[m][n] = __builtin_amdgcn_mfma_f32_16x16x32_bf16(a[m], b, acc[m][n], 0, 0, 0);
            }
        }
        __syncthreads();
        cur ^= 1;
    }

#pragma unroll
    for (int n = 0; n < 2; ++n) {
        int cg = n0 + wc * 32 + n * 16 + (lane & 15);
        float vb = bm[cg];
#pragma unroll
        for (int m = 0; m < 4; ++m) {
            int rbase = r0 + wr * 64 + m * 16 + ((lane >> 4) << 2);
#pragma unroll
            for (int j = 0; j < 4; ++j) {
                size_t off = (size_t)(rbase + j) * HDIM + cg;
                float z = acc[m][n][j] + vb;
                out[off] = bf2f(obuf[off]) * tanhfast(z);
            }
        }
    }
}

extern "C" void kernel_launch(void* const* d_in, const int* in_sizes, int n_in,
                              void* d_out, int out_size, void* d_ws, size_t ws_size,
                              hipStream_t stream) {
    const float* x  = (const float*)d_in[0];
    const float* h  = (const float*)d_in[1];
    const float* c  = (const float*)d_in[2];
    const float* C  = (const float*)d_in[3];
    const float* Wi = (const float*)d_in[4];  const float* bi  = (const float*)d_in[5];
    const float* Wf = (const float*)d_in[6];  const float* bf  = (const float*)d_in[7];
    const float* Wo = (const float*)d_in[8];  const float* bo  = (const float*)d_in[9];
    const float* Wg1 = (const float*)d_in[10]; const float* bg1 = (const float*)d_in[11];
    const float* Wg2 = (const float*)d_in[12]; const float* bg2 = (const float*)d_in[13];
    const float* Wm = (const float*)d_in[14]; const float* bm  = (const float*)d_in[15];
    float* out = (float*)d_out;

    unsigned short* wt    = (unsigned short*)d_ws;           // 6 x [512][1024] bf16 = 6 MB
    unsigned short* xh    = wt + (6u << 19);                 // [32768][1024] bf16 = 64 MB
    unsigned short* obuf  = xh + (size_t)BROWS * DIN;        // [32768][512]  bf16 = 32 MB
    unsigned short* ccbuf = obuf + HB;                       // [32768][1024] bf16 = 64 MB

    WP wp;
    wp.w[0] = Wi; wp.w[1] = Wf; wp.w[2] = Wo; wp.w[3] = Wg1; wp.w[4] = Wg2; wp.w[5] = Wm;

    cvt_xh<<<dim3(4096), dim3(256), 0, stream>>>(x, h, xh);
    wtrans<<<dim3(8, 16, 6), dim3(256), 0, stream>>>(wp, wt);
    gemm_gates<<<dim3(4096), dim3(256), 0, stream>>>(xh, wt, bi, bf, bo, bg1, bg2, c, C, out, obuf, ccbuf);
    gemm_mlp<<<dim3(2048), dim3(256), 0, stream>>>(ccbuf, wt + (5u << 19), bm, obuf, out);
}